// Round 10
// baseline (154.061 us; speedup 1.0000x reference)
//
#include <hip/hip_runtime.h>
#include <stdint.h>

#define NB 2
#define NS 2048
#define ND 1024
#define NH 16
#define NHD 64
#define NM (NB*NS)   // 4096

typedef __bf16 bf16;
typedef float f32x4 __attribute__((ext_vector_type(4)));
typedef __bf16 bf16x8 __attribute__((ext_vector_type(8)));
typedef __bf16 bf16x4 __attribute__((ext_vector_type(4)));

#define MFMA16(a,b,c) __builtin_amdgcn_mfma_f32_16x16x32_bf16(a,b,c,0,0,0)

__device__ __forceinline__ void gld_lds16(const bf16* g, bf16* l) {
  __builtin_amdgcn_global_load_lds((const __attribute__((address_space(1))) void*)g,
                                   (__attribute__((address_space(3))) void*)l,
                                   16, 0, 0);
}

// Barrier that drains LDS ops but leaves global loads in flight (vmcnt
// untouched) — unlike __syncthreads(), which drains vmcnt(0).
__device__ __forceinline__ void block_sync_lds() {
  asm volatile("s_waitcnt lgkmcnt(0)\n\ts_barrier" ::: "memory");
}

// ---------------- fp32 -> bf16 conversion, 3 equal tensors (Q,K,V) -------
__global__ __launch_bounds__(256)
void cvt3(const float* __restrict__ s0, const float* __restrict__ s1,
          const float* __restrict__ s2, bf16* __restrict__ dst, int n4each) {
  const int t = blockIdx.y;
  const float* s = (t == 0) ? s0 : (t == 1) ? s1 : s2;
  int i = blockIdx.x * blockDim.x + threadIdx.x;
  if (i >= n4each) return;
  float4 v = ((const float4*)s)[i];
  bf16x4 o = { (bf16)v.x, (bf16)v.y, (bf16)v.z, (bf16)v.w };
  ((bf16x4*)(dst + (size_t)t * n4each * 4))[i] = o;
}

// ---------------- fp32 -> bf16 conversion, 4 weight matrices --------------
__global__ __launch_bounds__(256)
void cvt_w4(const float* __restrict__ s0, const float* __restrict__ s1,
            const float* __restrict__ s2, const float* __restrict__ s3,
            bf16* __restrict__ dst, int n4each) {
  const int t = blockIdx.y;
  const float* s = (t == 0) ? s0 : (t == 1) ? s1 : (t == 2) ? s2 : s3;
  int i = blockIdx.x * blockDim.x + threadIdx.x;
  if (i >= n4each) return;
  float4 v = ((const float4*)s)[i];
  bf16x4 o = { (bf16)v.x, (bf16)v.y, (bf16)v.z, (bf16)v.w };
  ((bf16x4*)(dst + (size_t)t * n4each * 4))[i] = o;
}

// ---------------- QKV projection: 256x256 tile, BK=64, 8-phase pipeline ---
// T3+T4: per K-tile 4 phases {ds_read quad (+B at p0) | stage-issue at p0 |
// barrier | 16 MFMA (setprio)} ; single vmcnt(0) per tile at p3 — the only
// outstanding vmem is next tile's 8 gld_lds, issued 4 phases (~1000cy)
// earlier, so the drain is hidden. T2: st-swizzle via pre-swizzled global
// source (linear DMA dest) + XOR'd ds_read col: byte ^= (row&7)<<4 kills the
// 16-way conflict of 128B rows. T5: setprio around MFMA clusters.
// Fused RoPE (t<2) + (1/sqrt(HD))*log2(e) on q; bf16 out scattered [B,H,S,HD].
// Grid: 192 blocks, XCD-bijective (xcd = id&7 owns mt pair).
__global__ __launch_bounds__(512, 2)
void gemm_qkv(const bf16* __restrict__ A, const bf16* __restrict__ W,
              const float* __restrict__ b0, const float* __restrict__ b1,
              const float* __restrict__ b2,
              const float* __restrict__ fc, const float* __restrict__ fs,
              bf16* __restrict__ obf) {
  constexpr int K = ND;
  __shared__ __align__(16) bf16 As[2][256 * 64];   // 64 KB
  __shared__ __align__(16) bf16 Bs[2][256 * 64];   // 64 KB
  const int tid = threadIdx.x;
  const int w = tid >> 6, lane = tid & 63;

  // 192 = 8 xcd * { t(3) * [nt(4) * mtsub(2)] }
  const int id = blockIdx.x;
  const int xcd = id & 7, r = id >> 3;   // r 0..23
  const int t = r >> 3;                  // tensor 0..2
  const int rem = r & 7;
  const int nt = rem & 3;                // 0..3 (N=1024/256)
  const int mt = xcd * 2 + (rem >> 2);   // 0..15 (M=4096/256)

  const bf16* Ab = A + (size_t)t * ((size_t)NM * K) + (size_t)(mt * 256) * K;
  const bf16* Wb = W + (size_t)t * ((size_t)ND * K) + (size_t)(nt * 256) * K;
  const float* bias = (t == 0) ? b0 : (t == 1) ? b1 : b2;

  // staging: 512 thr cover 64 rows x 64 cols per gld_lds; 4 chunks per tensor
  const int srow = tid >> 3;                          // 0..63 within chunk
  const int scol = (((tid & 7) ^ (srow & 7)) << 3);   // swizzled source col
  const bf16* gA = Ab + (size_t)srow * K + scol;
  const bf16* gB = Wb + (size_t)srow * K + scol;
  const int seg = w * 512;   // wave-uniform LDS segment within 4096-elem chunk

  // fragment read bases; row&7 == lane&7 for all frags -> constant swizzle
  const int arow = (w >> 2) * 128 + (lane & 15);   // + m*16
  const int brow = (w & 3) * 64 + (lane & 15);     // + n*16
  const int swz = (lane & 7) << 3;
  const int cbase = (lane >> 4) * 8;               // + ks*32, then ^ swz

  f32x4 acc[8][4] = {};

  // prologue: tile 0 -> buf 0
#pragma unroll
  for (int c = 0; c < 4; ++c) {
    gld_lds16(gA + (size_t)(c * 64) * K, &As[0][c * 4096 + seg]);
    gld_lds16(gB + (size_t)(c * 64) * K, &Bs[0][c * 4096 + seg]);
  }
  asm volatile("s_waitcnt vmcnt(0)" ::: "memory");
  __builtin_amdgcn_s_barrier();

  for (int kt = 0; kt < 16; ++kt) {
    const int buf = kt & 1;
    bf16x8 bfr[4][2];
#pragma unroll
    for (int p = 0; p < 4; ++p) {
      if (p == 0) {
        if (kt + 1 < 16) {   // stage next tile into the other buffer
          const int k0 = (kt + 1) * 64;
#pragma unroll
          for (int c = 0; c < 4; ++c) {
            gld_lds16(gA + (size_t)(c * 64) * K + k0, &As[buf ^ 1][c * 4096 + seg]);
            gld_lds16(gB + (size_t)(c * 64) * K + k0, &Bs[buf ^ 1][c * 4096 + seg]);
          }
        }
#pragma unroll
        for (int n = 0; n < 4; ++n)
#pragma unroll
          for (int ks = 0; ks < 2; ++ks)
            bfr[n][ks] = *(const bf16x8*)
              &Bs[buf][(brow + n * 16) * 64 + ((cbase + ks * 32) ^ swz)];
      }
      bf16x8 af[2][2];
#pragma unroll
      for (int mm = 0; mm < 2; ++mm)
#pragma unroll
        for (int ks = 0; ks < 2; ++ks)
          af[mm][ks] = *(const bf16x8*)
            &As[buf][(arow + (2 * p + mm) * 16) * 64 + ((cbase + ks * 32) ^ swz)];
      __builtin_amdgcn_s_barrier();
      __builtin_amdgcn_s_setprio(1);
#pragma unroll
      for (int mm = 0; mm < 2; ++mm)
#pragma unroll
        for (int n = 0; n < 4; ++n)
#pragma unroll
          for (int ks = 0; ks < 2; ++ks)
            acc[2 * p + mm][n] = MFMA16(af[mm][ks], bfr[n][ks], acc[2 * p + mm][n]);
      __builtin_amdgcn_s_setprio(0);
      if (p == 3 && kt + 1 < 16)
        asm volatile("s_waitcnt vmcnt(0)" ::: "memory");   // next tile landed
      __builtin_amdgcn_s_barrier();
    }
  }

  // epilogue: bias + RoPE + scatter to [B,H,S,HD]
#pragma unroll
  for (int i = 0; i < 8; ++i) {
#pragma unroll
    for (int j = 0; j < 4; ++j) {
      const int gcol = nt * 256 + (w & 3) * 64 + j * 16 + (lane & 15);
      const float bv = bias[gcol];
#pragma unroll
      for (int r4 = 0; r4 < 4; ++r4) {
        const int grow = mt * 256 + (w >> 2) * 128 + i * 16 + (lane >> 4) * 4 + r4;
        float v = acc[i][j][r4] + bv;
        const int b = grow >> 11, s = grow & (NS - 1);
        const int h = gcol >> 6, hd = gcol & 63;
        if (t < 2) {   // fused RoPE: lane pairs hold adjacent hd columns
          float pv = __shfl_xor(v, 1);
          const int ii = hd >> 1;
          float c  = fc[(s << 5) + ii];
          float sn = fs[(s << 5) + ii];
          v = ((hd & 1) == 0) ? (v * c - pv * sn) : (pv * sn + v * c);
          if (t == 0) v *= 0.18033688011112042f;   // (1/sqrt(HD)) * log2(e)
        }
        obf[(size_t)t * ((size_t)NM * ND) +
            (((size_t)(b * NH + h) * NS + s) * NHD + hd)] = (bf16)v;
      }
    }
  }
}

// ---------------- out-proj GEMM (unchanged r9 structure) ------------------
template<int MODE>
__global__ __launch_bounds__(256)
void gemm_nt(const bf16* __restrict__ A, const bf16* __restrict__ W,
             const float* __restrict__ b0,
             float* __restrict__ of) {
  constexpr int K = ND;
  constexpr int BN = 64;
  constexpr int NJ = 2;
  constexpr int ITB = 2;
  __shared__ __align__(16) bf16 As[128 * 64];
  __shared__ __align__(16) bf16 Bs[BN * 64];
  const int tid = threadIdx.x;
  const int w = tid >> 6, lane = tid & 63;

  const int id = blockIdx.x;
  const int xcd = id & 7, r = id >> 3;
  const int nt = r & 15;
  const int mt = xcd + 8 * (r >> 4);

  const bf16* Ab = A;
  const bf16* Wb = W;
  const float* bias = b0;
  const int wr = (w >> 1) * 64, wc = (w & 1) * (BN / 2);
  f32x4 acc[4][NJ] = {};

  const bf16* ga = Ab + (size_t)(mt * 128 + w * 8 + (lane >> 3)) * K + (lane & 7) * 8;
  const bf16* gb = Wb + (size_t)(nt * BN + w * 8 + (lane >> 3)) * K + (lane & 7) * 8;

  for (int k0 = 0; k0 < K; k0 += 64) {
    __syncthreads();
#pragma unroll
    for (int it = 0; it < 4; ++it)
      gld_lds16(ga + (size_t)(it * 32) * K + k0, As + (it * 4 + w) * 512);
#pragma unroll
    for (int it = 0; it < ITB; ++it)
      gld_lds16(gb + (size_t)(it * 32) * K + k0, Bs + (it * 4 + w) * 512);
    __syncthreads();

#pragma unroll
    for (int ks = 0; ks < 2; ++ks) {
      bf16x8 af[4], bfr[NJ];
#pragma unroll
      for (int i = 0; i < 4; ++i)
        af[i] = *(const bf16x8*)&As[(wr + i * 16 + (lane & 15)) * 64 +
                                    ks * 32 + (lane >> 4) * 8];
#pragma unroll
      for (int j = 0; j < NJ; ++j)
        bfr[j] = *(const bf16x8*)&Bs[(wc + j * 16 + (lane & 15)) * 64 +
                                     ks * 32 + (lane >> 4) * 8];
#pragma unroll
      for (int i = 0; i < 4; ++i)
#pragma unroll
        for (int j = 0; j < NJ; ++j)
          acc[i][j] = MFMA16(af[i], bfr[j], acc[i][j]);
    }
  }

#pragma unroll
  for (int i = 0; i < 4; ++i) {
#pragma unroll
    for (int j = 0; j < NJ; ++j) {
      const int gcol = nt * BN + wc + j * 16 + (lane & 15);
      const float bv = bias[gcol];
#pragma unroll
      for (int r4 = 0; r4 < 4; ++r4) {
        const int grow = mt * 128 + wr + i * 16 + (lane >> 4) * 4 + r4;
        of[(size_t)grow * ND + gcol] = acc[i][j][r4] + bv;
      }
    }
  }
}

// ---------------- V transpose: [BH, S, 64] -> [BH, 64, S] ----------------
__global__ __launch_bounds__(256)
void transpose_v(const bf16* __restrict__ v, bf16* __restrict__ vt) {
  __shared__ __align__(16) bf16 t[64][72];
  const int s0 = blockIdx.x * 64;
  const int bh = blockIdx.y;
  const bf16* src = v + ((size_t)bh * NS + s0) * NHD;
#pragma unroll
  for (int it = 0; it < 2; ++it) {
    int slot = threadIdx.x + it * 256;
    int r = slot >> 3, c8 = (slot & 7) * 8;
    *(bf16x8*)&t[r][c8] = *(const bf16x8*)&src[(size_t)r * NHD + c8];
  }
  __syncthreads();
  bf16* dst = vt + (size_t)bh * NHD * NS + s0;
#pragma unroll
  for (int it = 0; it < 2; ++it) {
    int slot = threadIdx.x + it * 256;
    int r = slot >> 3, c8 = (slot & 7) * 8;   // r = hd row of output, c8 = s offset
    bf16x8 vv;
#pragma unroll
    for (int e = 0; e < 8; ++e) vv[e] = t[c8 + e][r];
    *(bf16x8*)&dst[(size_t)r * NS + c8] = vv;
  }
}

// ---------------- one 64-k-tile step for a 16-row q-subtile ---------------
__device__ __forceinline__ void attn_tile(
    const bf16 (*__restrict__ Ksh)[72], const bf16 (*__restrict__ Vsh)[72],
    bf16 (*__restrict__ Pw)[72], const bf16x8* qf, f32x4* o,
    float& m, float& l, int qi, int kk0, bool diag, int qrow, int grp) {
  f32x4 sc[4] = {};
  __builtin_amdgcn_s_setprio(1);
#pragma unroll
  for (int ch = 0; ch < 2; ++ch)
#pragma unroll
    for (int cb = 0; cb < 4; ++cb) {
      bf16x8 kf = *(const bf16x8*)&Ksh[cb * 16 + qrow][ch * 32 + grp * 8];
      sc[cb] = MFMA16(kf, qf[ch], sc[cb]);   // S^T[k][q]
    }
  __builtin_amdgcn_s_setprio(0);

  if (diag) {
#pragma unroll
    for (int cb = 0; cb < 4; ++cb)
#pragma unroll
      for (int r = 0; r < 4; ++r)
        if (kk0 + cb * 16 + grp * 4 + r > qi) sc[cb][r] = -1e30f;
  }

  float pm = sc[0][0];
#pragma unroll
  for (int cb = 0; cb < 4; ++cb)
#pragma unroll
    for (int r = 0; r < 4; ++r) pm = fmaxf(pm, sc[cb][r]);
  pm = fmaxf(pm, __shfl_xor(pm, 16));
  pm = fmaxf(pm, __shfl_xor(pm, 32));
  const float mn = fmaxf(m, pm);
  const float scl = exp2f(m - mn);
  m = mn;
  l *= scl;
#pragma unroll
  for (int cb = 0; cb < 4; ++cb) {
    bf16x4 pk;
#pragma unroll
    for (int r = 0; r < 4; ++r) {
      float p = exp2f(sc[cb][r] - mn);
      l += p;
      pk[r] = (bf16)p;
    }
    *(bf16x4*)&Pw[qrow][cb * 16 + grp * 4] = pk;
  }
#pragma unroll
  for (int hb = 0; hb < 4; ++hb)
#pragma unroll
    for (int r = 0; r < 4; ++r) o[hb][r] *= scl;

  __builtin_amdgcn_s_setprio(1);
#pragma unroll
  for (int ch = 0; ch < 2; ++ch) {
    bf16x8 pa = *(const bf16x8*)&Pw[qrow][ch * 32 + grp * 8];
#pragma unroll
    for (int hb = 0; hb < 4; ++hb) {
      bf16x8 vf = *(const bf16x8*)&Vsh[hb * 16 + qrow][ch * 32 + grp * 8];
      o[hb] = MFMA16(vf, pa, o[hb]);         // O^T[hd][q]
    }
  }
  __builtin_amdgcn_s_setprio(0);
}

// ---------------- flash attention, causal, 8 waves, k-parity split -------
__global__ __launch_bounds__(512, 4)
void attn_k(const bf16* __restrict__ q, const bf16* __restrict__ k,
            const bf16* __restrict__ vt, bf16* __restrict__ out) {
  __shared__ __align__(16) char smem[55296];
  auto Ks = (bf16(*)[64][72])smem;                 // [2][64][72] bf16
  auto Vs = (bf16(*)[64][72])(smem + 18432);       // [2][64][72] bf16
  auto P  = (bf16(*)[16][72])(smem + 36864);       // [8][16][72] bf16
  auto MO = (float(*)[2][16][68])smem;             // overlay [4][2][16][68] f32
  auto ML = (float(*)[2][16][2])(smem + 36864);    // overlay [4][2][16][2] f32

  const int tid = threadIdx.x;
  const int w = tid >> 6, lane = tid & 63;
  const int h = w >> 2, wl = w & 3;                // group, pair-index
  const int qrow = lane & 15, grp = lane >> 4;
  const int bh = blockIdx.x, j = blockIdx.y;
  const int b = bh >> 4, hh = bh & (NH - 1);
  const int tA = j, tB = 31 - j;

  const bf16* qb = q + (size_t)bh * NS * NHD;
  const bf16* kb = k + (size_t)bh * NS * NHD;
  const bf16* vb = vt + (size_t)bh * NHD * NS;

  const int nA = (j >= h) ? (((j - h) >> 1) + 1) : 0;   // group's tile-A rounds
  const int nB = (((31 - j) - h) >> 1) + 1;             // group's tile-B rounds
  const int len = nA + nB;                              // 17 (h=0) or 16 (h=1)

  const int q0A = tA * 64 + wl * 16, q0B = tB * 64 + wl * 16;
  bf16x8 qfA[2], qfB[2];
#pragma unroll
  for (int ch = 0; ch < 2; ++ch) {
    qfA[ch] = *(const bf16x8*)&qb[(size_t)(q0A + qrow) * NHD + ch * 32 + grp * 8];
    qfB[ch] = *(const bf16x8*)&qb[(size_t)(q0B + qrow) * NHD + ch * 32 + grp * 8];
  }

  f32x4 oA[4] = {}, oB[4] = {};
  float mA = -1e30f, lA = 0.f, mB = -1e30f, lB = 0.f;

  const int local = tid & 255;
  const int r0 = local >> 3, c0 = (local & 7) * 8;     // rows r0, r0+32

  bf16x8 ka0, ka1, va0, va1;
  auto load_round = [&](int r) {
    const bool isA = r < nA;
    const int kt = isA ? (h + 2 * r) : (h + 2 * (r - nA));
    const int kk0 = kt * 64;
    ka0 = *(const bf16x8*)&kb[(size_t)(kk0 + r0) * NHD + c0];
    ka1 = *(const bf16x8*)&kb[(size_t)(kk0 + r0 + 32) * NHD + c0];
    va0 = *(const bf16x8*)&vb[(size_t)r0 * NS + kk0 + c0];
    va1 = *(const bf16x8*)&vb[(size_t)(r0 + 32) * NS + kk0 + c0];
  };

  load_round(0);
  for (int r = 0; r < 17; ++r) {
    const bool act = r < len;
    if (act) {
      *(bf16x8*)&Ks[h][r0][c0]      = ka0;
      *(bf16x8*)&Ks[h][r0 + 32][c0] = ka1;
      *(bf16x8*)&Vs[h][r0][c0]      = va0;
      *(bf16x8*)&Vs[h][r0 + 32][c0] = va1;
    }
    block_sync_lds();                 // publish LDS; global loads stay in flight
    const bool isA = r < nA;
    const int kt = isA ? (h + 2 * r) : (h + 2 * (r - nA));
    if (r + 1 < len) load_round(r + 1);   // issue next loads under compute
    if (act) {
      if (isA)
        attn_tile(Ks[h], Vs[h], P[w], qfA, oA, mA, lA,
                  q0A + qrow, kt * 64, kt == tA, qrow, grp);
      else
        attn_tile(Ks[h], Vs[h], P[w], qfB, oB, mB, lB,
                  q0B + qrow, kt * 64, kt == tB, qrow, grp);
    }
    block_sync_lds();                 // readers done before next round's writes
  }

  lA += __shfl_xor(lA, 16); lA += __shfl_xor(lA, 32);
  lB += __shfl_xor(lB, 16); lB += __shfl_xor(lB, 32);

  __syncthreads();

  if (h == 1) {      // publish group-1 partials (fp32)
#pragma unroll
    for (int hb = 0; hb < 4; ++hb) {
      *(f32x4*)&MO[wl][0][qrow][hb * 16 + grp * 4] = oA[hb];
      *(f32x4*)&MO[wl][1][qrow][hb * 16 + grp * 4] = oB[hb];
    }
    if (grp == 0) {
      ML[wl][0][qrow][0] = mA; ML[wl][0][qrow][1] = lA;
      ML[wl][1][qrow][0] = mB; ML[wl][1][qrow][1] = lB;
    }
  }
  __syncthreads();

  if (h == 0) {      // merge + store
#pragma unroll
    for (int sub = 0; sub < 2; ++sub) {
      const float m0 = sub ? mB : mA, l0 = sub ? lB : lA;
      const f32x4* o0 = sub ? oB : oA;
      const float m1 = ML[wl][sub][qrow][0], l1 = ML[wl][sub][qrow][1];
      const float mm = fmaxf(m0, m1);
      const float s0 = exp2f(m0 - mm), s1 = exp2f(m1 - mm);
      const float inv = 1.f / (l0 * s0 + l1 * s1);
      const int s = (sub ? q0B : q0A) + qrow;
      bf16* op = out + (size_t)(b * NS + s) * ND + hh * NHD + grp * 4;
#pragma unroll
      for (int hb = 0; hb < 4; ++hb) {
        f32x4 o1 = *(const f32x4*)&MO[wl][sub][qrow][hb * 16 + grp * 4];
        bf16x4 ov = { (bf16)((o0[hb][0] * s0 + o1[0] * s1) * inv),
                      (bf16)((o0[hb][1] * s0 + o1[1] * s1) * inv),
                      (bf16)((o0[hb][2] * s0 + o1[2] * s1) * inv),
                      (bf16)((o0[hb][3] * s0 + o1[3] * s1) * inv) };
        *(bf16x4*)&op[hb * 16] = ov;
      }
    }
  }
}

// -------------------------------------------------------------------------
extern "C" void kernel_launch(void* const* d_in, const int* in_sizes, int n_in,
                              void* d_out, int out_size, void* d_ws, size_t ws_size,
                              hipStream_t stream) {
  const float* Q  = (const float*)d_in[0];
  const float* K  = (const float*)d_in[1];
  const float* V  = (const float*)d_in[2];
  // d_in[3] = mask (causal, known analytically -> unused)
  const float* fc = (const float*)d_in[4];
  const float* fs = (const float*)d_in[5];
  const float* wq = (const float*)d_in[6];
  const float* bq = (const float*)d_in[7];
  const float* wk = (const float*)d_in[8];
  const float* bk = (const float*)d_in[9];
  const float* wv = (const float*)d_in[10];
  const float* bv = (const float*)d_in[11];
  const float* wo = (const float*)d_in[12];
  const float* bo = (const float*)d_in[13];
  float* out = (float*)d_out;
  bf16* ws = (bf16*)d_ws;

  const size_t MB_ = 1024 * 1024;  // elements
  bf16* Qbf  = ws;                     // 3 x 4M elems (Q,K,V bf16)
  bf16* Wqkv = ws + 12 * MB_;          // 3 x 1M (wq, wk, wv)
  bf16* Wo   = ws + 15 * MB_;          // 1M
  bf16* qp   = ws + 16 * MB_;          // q' [BH,S,HD] 4M
  bf16* kp   = ws + 20 * MB_;          // k' 4M
  bf16* vp   = ws + 24 * MB_;          // v' 4M
  bf16* vtp  = ws + 28 * MB_;          // v transposed [BH,HD,S] 4M
  bf16* aout = ws + 32 * MB_;          // attention output [M, D] 4M

  cvt3<<<dim3(4096, 3), 256, 0, stream>>>(Q, K, V, Qbf, 1048576);
  cvt_w4<<<dim3(1024, 4), 256, 0, stream>>>(wq, wk, wv, wo, Wqkv, 262144);

  gemm_qkv<<<192, 512, 0, stream>>>(Qbf, Wqkv, bq, bk, bv, fc, fs, qp);

  transpose_v<<<dim3(32, 32), 256, 0, stream>>>(vp, vtp);

  attn_k<<<dim3(32, 16), 512, 0, stream>>>(qp, kp, vtp, aout);

  gemm_nt<1><<<512, 256, 0, stream>>>(aout, Wo, bo, out);
}

// Round 11
// 126.324 us; speedup vs baseline: 1.2196x; 1.2196x over previous
//
#include <hip/hip_runtime.h>
#include <stdint.h>

#define NB 2
#define NS 2048
#define ND 1024
#define NH 16
#define NHD 64
#define NM (NB*NS)   // 4096

typedef __bf16 bf16;
typedef float f32x4 __attribute__((ext_vector_type(4)));
typedef __bf16 bf16x8 __attribute__((ext_vector_type(8)));
typedef __bf16 bf16x4 __attribute__((ext_vector_type(4)));

#define MFMA16(a,b,c) __builtin_amdgcn_mfma_f32_16x16x32_bf16(a,b,c,0,0,0)

__device__ __forceinline__ void gld_lds16(const bf16* g, bf16* l) {
  __builtin_amdgcn_global_load_lds((const __attribute__((address_space(1))) void*)g,
                                   (__attribute__((address_space(3))) void*)l,
                                   16, 0, 0);
}

// Barrier that drains LDS ops but leaves global loads in flight (vmcnt
// untouched) — unlike __syncthreads(), which drains vmcnt(0).
__device__ __forceinline__ void block_sync_lds() {
  asm volatile("s_waitcnt lgkmcnt(0)\n\ts_barrier" ::: "memory");
}

// ---------------- fp32 -> bf16 conversion, 3 equal tensors (Q,K,V) -------
__global__ __launch_bounds__(256)
void cvt3(const float* __restrict__ s0, const float* __restrict__ s1,
          const float* __restrict__ s2, bf16* __restrict__ dst, int n4each) {
  const int t = blockIdx.y;
  const float* s = (t == 0) ? s0 : (t == 1) ? s1 : s2;
  int i = blockIdx.x * blockDim.x + threadIdx.x;
  if (i >= n4each) return;
  float4 v = ((const float4*)s)[i];
  bf16x4 o = { (bf16)v.x, (bf16)v.y, (bf16)v.z, (bf16)v.w };
  ((bf16x4*)(dst + (size_t)t * n4each * 4))[i] = o;
}

// ---------------- fp32 -> bf16 conversion, 4 weight matrices --------------
__global__ __launch_bounds__(256)
void cvt_w4(const float* __restrict__ s0, const float* __restrict__ s1,
            const float* __restrict__ s2, const float* __restrict__ s3,
            bf16* __restrict__ dst, int n4each) {
  const int t = blockIdx.y;
  const float* s = (t == 0) ? s0 : (t == 1) ? s1 : (t == 2) ? s2 : s3;
  int i = blockIdx.x * blockDim.x + threadIdx.x;
  if (i >= n4each) return;
  float4 v = ((const float4*)s)[i];
  bf16x4 o = { (bf16)v.x, (bf16)v.y, (bf16)v.z, (bf16)v.w };
  ((bf16x4*)(dst + (size_t)t * n4each * 4))[i] = o;
}

// ---------------- NT GEMM: C[m,n] = sum_k A[m,k]*W[n,k] + bias[n] --------
// r9 2-phase structure (768/512 blocks = full coverage, 32 KB LDS, 3/CU)
// + T2 swizzle (r10-proven): global source col-chunk ^= (row&7), LDS dest
// linear (gld_lds requirement), ds_read col-chunk ^= (row&7) -> the 16-way
// conflict of 128B LDS rows at BK=64 becomes conflict-free.
// MODE 0: QKV projection; fused RoPE (t<2); q scaled by (1/sqrt(HD))*log2(e);
//         t<2 -> bf16 scatter [B,H,S,HD]; t==2 (V) -> DIRECT [BH,HD,S]
//         transposed write (replaces the transpose_v kernel).
// MODE 1: output projection (128x64 tile), fp32 out [M, D]
template<int MODE>
__global__ __launch_bounds__(256)
void gemm_nt(const bf16* __restrict__ A, const bf16* __restrict__ W,
             const float* __restrict__ b0, const float* __restrict__ b1,
             const float* __restrict__ b2,
             const float* __restrict__ fc, const float* __restrict__ fs,
             bf16* __restrict__ obf, bf16* __restrict__ vtp,
             float* __restrict__ of) {
  constexpr int K = ND;
  constexpr int BN = (MODE == 0) ? 128 : 64;
  constexpr int NJ = (MODE == 0) ? 4 : 2;      // N-fragments per wave
  constexpr int ITB = (MODE == 0) ? 4 : 2;     // B staging chunks per thread
  __shared__ __align__(16) bf16 As[128 * 64];
  __shared__ __align__(16) bf16 Bs[BN * 64];
  const int tid = threadIdx.x;
  const int w = tid >> 6, lane = tid & 63;

  // XCD-bijective block decode (hardware round-robins linear id % 8)
  const int id = blockIdx.x;
  const int xcd = id & 7, r = id >> 3;
  int t, nt, mt;
  if (MODE == 0) { t = r >> 5; const int rem = r & 31; nt = rem & 7;  mt = xcd + 8 * (rem >> 3); }
  else           { t = 0;                              nt = r & 15;   mt = xcd + 8 * (r >> 4);   }

  const bf16* Ab = A + (size_t)t * ((size_t)NM * K);
  const bf16* Wb = W + (size_t)t * ((size_t)ND * K);
  const float* bias = (t == 0) ? b0 : (t == 1) ? b1 : b2;
  const int wr = (w >> 1) * 64, wc = (w & 1) * (BN / 2);
  f32x4 acc[4][NJ] = {};

  // T2: source col-chunk pre-swizzled by row&7 (row&7 == (lane>>3)&7 here);
  // LDS dest stays linear (DMA writes base + lane*16).
  const int swsrc = (((lane & 7) ^ ((lane >> 3) & 7)) << 3);
  const bf16* ga = Ab + (size_t)(mt * 128 + w * 8 + (lane >> 3)) * K + swsrc;
  const bf16* gb = Wb + (size_t)(nt * BN + w * 8 + (lane >> 3)) * K + swsrc;

  for (int k0 = 0; k0 < K; k0 += 64) {
    __syncthreads();   // readers of previous tile done
#pragma unroll
    for (int it = 0; it < 4; ++it)
      gld_lds16(ga + (size_t)(it * 32) * K + k0, As + (it * 4 + w) * 512);
#pragma unroll
    for (int it = 0; it < ITB; ++it)
      gld_lds16(gb + (size_t)(it * 32) * K + k0, Bs + (it * 4 + w) * 512);
    __syncthreads();   // drains vmcnt(0) -> LDS ready for all waves

#pragma unroll
    for (int ks = 0; ks < 2; ++ks) {   // two K=32 sub-rounds keep VGPR low
      bf16x8 af[4], bfr[NJ];
#pragma unroll
      for (int i = 0; i < 4; ++i) {
        const int row = wr + i * 16 + (lane & 15);     // row&7 == lane&7
        af[i] = *(const bf16x8*)&As[row * 64 +
                 (((ks * 4 + (lane >> 4)) ^ (lane & 7)) << 3)];
      }
#pragma unroll
      for (int j = 0; j < NJ; ++j) {
        const int row = wc + j * 16 + (lane & 15);
        bfr[j] = *(const bf16x8*)&Bs[row * 64 +
                  (((ks * 4 + (lane >> 4)) ^ (lane & 7)) << 3)];
      }
#pragma unroll
      for (int i = 0; i < 4; ++i)
#pragma unroll
        for (int j = 0; j < NJ; ++j)
          acc[i][j] = MFMA16(af[i], bfr[j], acc[i][j]);
    }
  }

#pragma unroll
  for (int i = 0; i < 4; ++i) {
#pragma unroll
    for (int j = 0; j < NJ; ++j) {
      const int gcol = nt * BN + wc + j * 16 + (lane & 15);
      const float bv = bias[gcol];
      if (MODE == 0 && t == 2) {
        // V: write transposed [BH, HD, S] directly (4 consecutive s per lane)
        const int s0g = mt * 128 + wr + i * 16 + (lane >> 4) * 4;
        const int b = s0g >> 11, s = s0g & (NS - 1);
        const int h = gcol >> 6, hd = gcol & 63;
        bf16x4 pk = { (bf16)(acc[i][j][0] + bv), (bf16)(acc[i][j][1] + bv),
                      (bf16)(acc[i][j][2] + bv), (bf16)(acc[i][j][3] + bv) };
        *(bf16x4*)&vtp[((size_t)(b * NH + h) * NHD + hd) * NS + s] = pk;
        continue;
      }
#pragma unroll
      for (int r4 = 0; r4 < 4; ++r4) {
        const int grow = mt * 128 + wr + i * 16 + (lane >> 4) * 4 + r4;
        float v = acc[i][j][r4] + bv;
        if (MODE == 0) {
          const int b = grow >> 11, s = grow & (NS - 1);
          const int h = gcol >> 6, hd = gcol & 63;
          // fused RoPE: lane pairs hold adjacent hd columns
          float pv = __shfl_xor(v, 1);
          const int ii = hd >> 1;
          float c  = fc[(s << 5) + ii];
          float sn = fs[(s << 5) + ii];
          // even hd: out_r = xr*c - xi*s   (v=xr, pv=xi)
          // odd  hd: out_i = xr*s + xi*c   (v=xi, pv=xr)
          v = ((hd & 1) == 0) ? (v * c - pv * sn) : (pv * sn + v * c);
          if (t == 0) v *= 0.18033688011112042f;   // (1/sqrt(HD)) * log2(e)
          obf[(size_t)t * ((size_t)NM * ND) +
              (((size_t)(b * NH + h) * NS + s) * NHD + hd)] = (bf16)v;
        } else {
          of[(size_t)grow * ND + gcol] = v;
        }
      }
    }
  }
}

// ---------------- one 64-k-tile step for a 16-row q-subtile ---------------
__device__ __forceinline__ void attn_tile(
    const bf16 (*__restrict__ Ksh)[72], const bf16 (*__restrict__ Vsh)[72],
    bf16 (*__restrict__ Pw)[72], const bf16x8* qf, f32x4* o,
    float& m, float& l, int qi, int kk0, bool diag, int qrow, int grp) {
  f32x4 sc[4] = {};
  __builtin_amdgcn_s_setprio(1);
#pragma unroll
  for (int ch = 0; ch < 2; ++ch)
#pragma unroll
    for (int cb = 0; cb < 4; ++cb) {
      bf16x8 kf = *(const bf16x8*)&Ksh[cb * 16 + qrow][ch * 32 + grp * 8];
      sc[cb] = MFMA16(kf, qf[ch], sc[cb]);   // S^T[k][q]
    }
  __builtin_amdgcn_s_setprio(0);

  if (diag) {
#pragma unroll
    for (int cb = 0; cb < 4; ++cb)
#pragma unroll
      for (int r = 0; r < 4; ++r)
        if (kk0 + cb * 16 + grp * 4 + r > qi) sc[cb][r] = -1e30f;
  }

  float pm = sc[0][0];
#pragma unroll
  for (int cb = 0; cb < 4; ++cb)
#pragma unroll
    for (int r = 0; r < 4; ++r) pm = fmaxf(pm, sc[cb][r]);
  pm = fmaxf(pm, __shfl_xor(pm, 16));
  pm = fmaxf(pm, __shfl_xor(pm, 32));
  const float mn = fmaxf(m, pm);
  const float scl = exp2f(m - mn);
  m = mn;
  l *= scl;
#pragma unroll
  for (int cb = 0; cb < 4; ++cb) {
    bf16x4 pk;
#pragma unroll
    for (int r = 0; r < 4; ++r) {
      float p = exp2f(sc[cb][r] - mn);
      l += p;
      pk[r] = (bf16)p;
    }
    *(bf16x4*)&Pw[qrow][cb * 16 + grp * 4] = pk;
  }
#pragma unroll
  for (int hb = 0; hb < 4; ++hb)
#pragma unroll
    for (int r = 0; r < 4; ++r) o[hb][r] *= scl;

  __builtin_amdgcn_s_setprio(1);
#pragma unroll
  for (int ch = 0; ch < 2; ++ch) {
    bf16x8 pa = *(const bf16x8*)&Pw[qrow][ch * 32 + grp * 8];
#pragma unroll
    for (int hb = 0; hb < 4; ++hb) {
      bf16x8 vf = *(const bf16x8*)&Vsh[hb * 16 + qrow][ch * 32 + grp * 8];
      o[hb] = MFMA16(vf, pa, o[hb]);         // O^T[hd][q]
    }
  }
  __builtin_amdgcn_s_setprio(0);
}

// ---------------- flash attention, causal, 8 waves, k-parity split -------
__global__ __launch_bounds__(512, 4)
void attn_k(const bf16* __restrict__ q, const bf16* __restrict__ k,
            const bf16* __restrict__ vt, bf16* __restrict__ out) {
  __shared__ __align__(16) char smem[55296];
  auto Ks = (bf16(*)[64][72])smem;                 // [2][64][72] bf16
  auto Vs = (bf16(*)[64][72])(smem + 18432);       // [2][64][72] bf16
  auto P  = (bf16(*)[16][72])(smem + 36864);       // [8][16][72] bf16
  auto MO = (float(*)[2][16][68])smem;             // overlay [4][2][16][68] f32
  auto ML = (float(*)[2][16][2])(smem + 36864);    // overlay [4][2][16][2] f32

  const int tid = threadIdx.x;
  const int w = tid >> 6, lane = tid & 63;
  const int h = w >> 2, wl = w & 3;                // group, pair-index
  const int qrow = lane & 15, grp = lane >> 4;
  const int bh = blockIdx.x, j = blockIdx.y;
  const int b = bh >> 4, hh = bh & (NH - 1);
  const int tA = j, tB = 31 - j;

  const bf16* qb = q + (size_t)bh * NS * NHD;
  const bf16* kb = k + (size_t)bh * NS * NHD;
  const bf16* vb = vt + (size_t)bh * NHD * NS;

  const int nA = (j >= h) ? (((j - h) >> 1) + 1) : 0;   // group's tile-A rounds
  const int nB = (((31 - j) - h) >> 1) + 1;             // group's tile-B rounds
  const int len = nA + nB;                              // 17 (h=0) or 16 (h=1)

  const int q0A = tA * 64 + wl * 16, q0B = tB * 64 + wl * 16;
  bf16x8 qfA[2], qfB[2];
#pragma unroll
  for (int ch = 0; ch < 2; ++ch) {
    qfA[ch] = *(const bf16x8*)&qb[(size_t)(q0A + qrow) * NHD + ch * 32 + grp * 8];
    qfB[ch] = *(const bf16x8*)&qb[(size_t)(q0B + qrow) * NHD + ch * 32 + grp * 8];
  }

  f32x4 oA[4] = {}, oB[4] = {};
  float mA = -1e30f, lA = 0.f, mB = -1e30f, lB = 0.f;

  const int local = tid & 255;
  const int r0 = local >> 3, c0 = (local & 7) * 8;     // rows r0, r0+32

  bf16x8 ka0, ka1, va0, va1;
  auto load_round = [&](int r) {
    const bool isA = r < nA;
    const int kt = isA ? (h + 2 * r) : (h + 2 * (r - nA));
    const int kk0 = kt * 64;
    ka0 = *(const bf16x8*)&kb[(size_t)(kk0 + r0) * NHD + c0];
    ka1 = *(const bf16x8*)&kb[(size_t)(kk0 + r0 + 32) * NHD + c0];
    va0 = *(const bf16x8*)&vb[(size_t)r0 * NS + kk0 + c0];
    va1 = *(const bf16x8*)&vb[(size_t)(r0 + 32) * NS + kk0 + c0];
  };

  load_round(0);
  for (int r = 0; r < 17; ++r) {
    const bool act = r < len;
    if (act) {
      *(bf16x8*)&Ks[h][r0][c0]      = ka0;
      *(bf16x8*)&Ks[h][r0 + 32][c0] = ka1;
      *(bf16x8*)&Vs[h][r0][c0]      = va0;
      *(bf16x8*)&Vs[h][r0 + 32][c0] = va1;
    }
    block_sync_lds();                 // publish LDS; global loads stay in flight
    const bool isA = r < nA;
    const int kt = isA ? (h + 2 * r) : (h + 2 * (r - nA));
    if (r + 1 < len) load_round(r + 1);   // issue next loads under compute
    if (act) {
      if (isA)
        attn_tile(Ks[h], Vs[h], P[w], qfA, oA, mA, lA,
                  q0A + qrow, kt * 64, kt == tA, qrow, grp);
      else
        attn_tile(Ks[h], Vs[h], P[w], qfB, oB, mB, lB,
                  q0B + qrow, kt * 64, kt == tB, qrow, grp);
    }
    block_sync_lds();                 // readers done before next round's writes
  }

  lA += __shfl_xor(lA, 16); lA += __shfl_xor(lA, 32);
  lB += __shfl_xor(lB, 16); lB += __shfl_xor(lB, 32);

  __syncthreads();

  if (h == 1) {      // publish group-1 partials (fp32)
#pragma unroll
    for (int hb = 0; hb < 4; ++hb) {
      *(f32x4*)&MO[wl][0][qrow][hb * 16 + grp * 4] = oA[hb];
      *(f32x4*)&MO[wl][1][qrow][hb * 16 + grp * 4] = oB[hb];
    }
    if (grp == 0) {
      ML[wl][0][qrow][0] = mA; ML[wl][0][qrow][1] = lA;
      ML[wl][1][qrow][0] = mB; ML[wl][1][qrow][1] = lB;
    }
  }
  __syncthreads();

  if (h == 0) {      // merge + store
#pragma unroll
    for (int sub = 0; sub < 2; ++sub) {
      const float m0 = sub ? mB : mA, l0 = sub ? lB : lA;
      const f32x4* o0 = sub ? oB : oA;
      const float m1 = ML[wl][sub][qrow][0], l1 = ML[wl][sub][qrow][1];
      const float mm = fmaxf(m0, m1);
      const float s0 = exp2f(m0 - mm), s1 = exp2f(m1 - mm);
      const float inv = 1.f / (l0 * s0 + l1 * s1);
      const int s = (sub ? q0B : q0A) + qrow;
      bf16* op = out + (size_t)(b * NS + s) * ND + hh * NHD + grp * 4;
#pragma unroll
      for (int hb = 0; hb < 4; ++hb) {
        f32x4 o1 = *(const f32x4*)&MO[wl][sub][qrow][hb * 16 + grp * 4];
        bf16x4 ov = { (bf16)((o0[hb][0] * s0 + o1[0] * s1) * inv),
                      (bf16)((o0[hb][1] * s0 + o1[1] * s1) * inv),
                      (bf16)((o0[hb][2] * s0 + o1[2] * s1) * inv),
                      (bf16)((o0[hb][3] * s0 + o1[3] * s1) * inv) };
        *(bf16x4*)&op[hb * 16] = ov;
      }
    }
  }
}

// -------------------------------------------------------------------------
extern "C" void kernel_launch(void* const* d_in, const int* in_sizes, int n_in,
                              void* d_out, int out_size, void* d_ws, size_t ws_size,
                              hipStream_t stream) {
  const float* Q  = (const float*)d_in[0];
  const float* K  = (const float*)d_in[1];
  const float* V  = (const float*)d_in[2];
  // d_in[3] = mask (causal, known analytically -> unused)
  const float* fc = (const float*)d_in[4];
  const float* fs = (const float*)d_in[5];
  const float* wq = (const float*)d_in[6];
  const float* bq = (const float*)d_in[7];
  const float* wk = (const float*)d_in[8];
  const float* bk = (const float*)d_in[9];
  const float* wv = (const float*)d_in[10];
  const float* bv = (const float*)d_in[11];
  const float* wo = (const float*)d_in[12];
  const float* bo = (const float*)d_in[13];
  float* out = (float*)d_out;
  bf16* ws = (bf16*)d_ws;

  const size_t MB_ = 1024 * 1024;  // elements
  bf16* Qbf  = ws;                     // 3 x 4M elems (Q,K,V bf16)
  bf16* Wqkv = ws + 12 * MB_;          // 3 x 1M (wq, wk, wv)
  bf16* Wo   = ws + 15 * MB_;          // 1M
  bf16* qp   = ws + 16 * MB_;          // q' [BH,S,HD] 4M (k' at +4M)
  bf16* vtp  = ws + 28 * MB_;          // v transposed [BH,HD,S] 4M (direct)
  bf16* aout = ws + 32 * MB_;          // attention output [M, D] 4M
  bf16* kp   = ws + 20 * MB_;

  cvt3<<<dim3(4096, 3), 256, 0, stream>>>(Q, K, V, Qbf, 1048576);
  cvt_w4<<<dim3(1024, 4), 256, 0, stream>>>(wq, wk, wv, wo, Wqkv, 262144);

  gemm_nt<0><<<768, 256, 0, stream>>>(Qbf, Wqkv, bq, bk, bv, fc, fs,
                                      qp, vtp, nullptr);

  attn_k<<<dim3(32, 16), 512, 0, stream>>>(qp, kp, vtp, aout);

  gemm_nt<1><<<512, 256, 0, stream>>>(aout, Wo, bo, bo, bo, fc, fs,
                                      nullptr, nullptr, out);
}

// Round 12
// 122.190 us; speedup vs baseline: 1.2608x; 1.0338x over previous
//
#include <hip/hip_runtime.h>
#include <stdint.h>

#define NB 2
#define NS 2048
#define ND 1024
#define NH 16
#define NHD 64
#define NM (NB*NS)   // 4096

typedef __bf16 bf16;
typedef float f32x4 __attribute__((ext_vector_type(4)));
typedef __bf16 bf16x8 __attribute__((ext_vector_type(8)));
typedef __bf16 bf16x4 __attribute__((ext_vector_type(4)));

#define MFMA16(a,b,c) __builtin_amdgcn_mfma_f32_16x16x32_bf16(a,b,c,0,0,0)

__device__ __forceinline__ void gld_lds16(const bf16* g, bf16* l) {
  __builtin_amdgcn_global_load_lds((const __attribute__((address_space(1))) void*)g,
                                   (__attribute__((address_space(3))) void*)l,
                                   16, 0, 0);
}

// Barrier that drains LDS ops but leaves global loads in flight (vmcnt
// untouched) — unlike __syncthreads(), which drains vmcnt(0).
__device__ __forceinline__ void block_sync_lds() {
  asm volatile("s_waitcnt lgkmcnt(0)\n\ts_barrier" ::: "memory");
}

// ---------------- fp32 -> bf16 conversion, 3 equal tensors (Q,K,V) -------
__global__ __launch_bounds__(256)
void cvt3(const float* __restrict__ s0, const float* __restrict__ s1,
          const float* __restrict__ s2, bf16* __restrict__ dst, int n4each) {
  const int t = blockIdx.y;
  const float* s = (t == 0) ? s0 : (t == 1) ? s1 : s2;
  int i = blockIdx.x * blockDim.x + threadIdx.x;
  if (i >= n4each) return;
  float4 v = ((const float4*)s)[i];
  bf16x4 o = { (bf16)v.x, (bf16)v.y, (bf16)v.z, (bf16)v.w };
  ((bf16x4*)(dst + (size_t)t * n4each * 4))[i] = o;
}

// ---------------- fp32 -> bf16 conversion, 4 weight matrices --------------
__global__ __launch_bounds__(256)
void cvt_w4(const float* __restrict__ s0, const float* __restrict__ s1,
            const float* __restrict__ s2, const float* __restrict__ s3,
            bf16* __restrict__ dst, int n4each) {
  const int t = blockIdx.y;
  const float* s = (t == 0) ? s0 : (t == 1) ? s1 : (t == 2) ? s2 : s3;
  int i = blockIdx.x * blockDim.x + threadIdx.x;
  if (i >= n4each) return;
  float4 v = ((const float4*)s)[i];
  bf16x4 o = { (bf16)v.x, (bf16)v.y, (bf16)v.z, (bf16)v.w };
  ((bf16x4*)(dst + (size_t)t * n4each * 4))[i] = o;
}

// ---------------- NT GEMM (unchanged r11: 2-phase + T2 swizzle) -----------
// MODE 0: QKV projection; fused RoPE (t<2); q scaled by (1/sqrt(HD))*log2(e);
//         t<2 -> bf16 scatter [B,H,S,HD]; t==2 (V) -> DIRECT [BH,HD,S].
// MODE 1: output projection (128x64 tile), fp32 out [M, D]
template<int MODE>
__global__ __launch_bounds__(256)
void gemm_nt(const bf16* __restrict__ A, const bf16* __restrict__ W,
             const float* __restrict__ b0, const float* __restrict__ b1,
             const float* __restrict__ b2,
             const float* __restrict__ fc, const float* __restrict__ fs,
             bf16* __restrict__ obf, bf16* __restrict__ vtp,
             float* __restrict__ of) {
  constexpr int K = ND;
  constexpr int BN = (MODE == 0) ? 128 : 64;
  constexpr int NJ = (MODE == 0) ? 4 : 2;      // N-fragments per wave
  constexpr int ITB = (MODE == 0) ? 4 : 2;     // B staging chunks per thread
  __shared__ __align__(16) bf16 As[128 * 64];
  __shared__ __align__(16) bf16 Bs[BN * 64];
  const int tid = threadIdx.x;
  const int w = tid >> 6, lane = tid & 63;

  // XCD-bijective block decode (hardware round-robins linear id % 8)
  const int id = blockIdx.x;
  const int xcd = id & 7, r = id >> 3;
  int t, nt, mt;
  if (MODE == 0) { t = r >> 5; const int rem = r & 31; nt = rem & 7;  mt = xcd + 8 * (rem >> 3); }
  else           { t = 0;                              nt = r & 15;   mt = xcd + 8 * (r >> 4);   }

  const bf16* Ab = A + (size_t)t * ((size_t)NM * K);
  const bf16* Wb = W + (size_t)t * ((size_t)ND * K);
  const float* bias = (t == 0) ? b0 : (t == 1) ? b1 : b2;
  const int wr = (w >> 1) * 64, wc = (w & 1) * (BN / 2);
  f32x4 acc[4][NJ] = {};

  // T2: source col-chunk pre-swizzled by row&7; LDS dest stays linear (DMA).
  const int swsrc = (((lane & 7) ^ ((lane >> 3) & 7)) << 3);
  const bf16* ga = Ab + (size_t)(mt * 128 + w * 8 + (lane >> 3)) * K + swsrc;
  const bf16* gb = Wb + (size_t)(nt * BN + w * 8 + (lane >> 3)) * K + swsrc;

  for (int k0 = 0; k0 < K; k0 += 64) {
    __syncthreads();   // readers of previous tile done
#pragma unroll
    for (int it = 0; it < 4; ++it)
      gld_lds16(ga + (size_t)(it * 32) * K + k0, As + (it * 4 + w) * 512);
#pragma unroll
    for (int it = 0; it < ITB; ++it)
      gld_lds16(gb + (size_t)(it * 32) * K + k0, Bs + (it * 4 + w) * 512);
    __syncthreads();   // drains vmcnt(0) -> LDS ready for all waves

#pragma unroll
    for (int ks = 0; ks < 2; ++ks) {
      bf16x8 af[4], bfr[NJ];
#pragma unroll
      for (int i = 0; i < 4; ++i) {
        const int row = wr + i * 16 + (lane & 15);
        af[i] = *(const bf16x8*)&As[row * 64 +
                 (((ks * 4 + (lane >> 4)) ^ (lane & 7)) << 3)];
      }
#pragma unroll
      for (int j = 0; j < NJ; ++j) {
        const int row = wc + j * 16 + (lane & 15);
        bfr[j] = *(const bf16x8*)&Bs[row * 64 +
                  (((ks * 4 + (lane >> 4)) ^ (lane & 7)) << 3)];
      }
#pragma unroll
      for (int i = 0; i < 4; ++i)
#pragma unroll
        for (int j = 0; j < NJ; ++j)
          acc[i][j] = MFMA16(af[i], bfr[j], acc[i][j]);
    }
  }

#pragma unroll
  for (int i = 0; i < 4; ++i) {
#pragma unroll
    for (int j = 0; j < NJ; ++j) {
      const int gcol = nt * BN + wc + j * 16 + (lane & 15);
      const float bv = bias[gcol];
      if (MODE == 0 && t == 2) {
        const int s0g = mt * 128 + wr + i * 16 + (lane >> 4) * 4;
        const int b = s0g >> 11, s = s0g & (NS - 1);
        const int h = gcol >> 6, hd = gcol & 63;
        bf16x4 pk = { (bf16)(acc[i][j][0] + bv), (bf16)(acc[i][j][1] + bv),
                      (bf16)(acc[i][j][2] + bv), (bf16)(acc[i][j][3] + bv) };
        *(bf16x4*)&vtp[((size_t)(b * NH + h) * NHD + hd) * NS + s] = pk;
        continue;
      }
#pragma unroll
      for (int r4 = 0; r4 < 4; ++r4) {
        const int grow = mt * 128 + wr + i * 16 + (lane >> 4) * 4 + r4;
        float v = acc[i][j][r4] + bv;
        if (MODE == 0) {
          const int b = grow >> 11, s = grow & (NS - 1);
          const int h = gcol >> 6, hd = gcol & 63;
          float pv = __shfl_xor(v, 1);
          const int ii = hd >> 1;
          float c  = fc[(s << 5) + ii];
          float sn = fs[(s << 5) + ii];
          v = ((hd & 1) == 0) ? (v * c - pv * sn) : (pv * sn + v * c);
          if (t == 0) v *= 0.18033688011112042f;   // (1/sqrt(HD)) * log2(e)
          obf[(size_t)t * ((size_t)NM * ND) +
              (((size_t)(b * NH + h) * NS + s) * NHD + hd)] = (bf16)v;
        } else {
          of[(size_t)grow * ND + gcol] = v;
        }
      }
    }
  }
}

// ---------------- one 64-k-tile step for a 16-row q-subtile ---------------
// K/V/P in XOR-swizzled [*][64] LDS (chunk8 ^= row&7). Defer-max (T13):
// skip cross-lane max + rescale unless some lane's tile-max exceeds m+8.
__device__ __forceinline__ void attn_tile(
    const bf16* __restrict__ Ksh, const bf16* __restrict__ Vsh,
    bf16* __restrict__ Pw, const bf16x8* qf, f32x4* o,
    float& m, float& l, int qi, int kk0, bool diag, int qrow, int grp) {
  const int s7 = qrow & 7;
  f32x4 sc[4] = {};
  __builtin_amdgcn_s_setprio(1);
#pragma unroll
  for (int ch = 0; ch < 2; ++ch)
#pragma unroll
    for (int cb = 0; cb < 4; ++cb) {
      bf16x8 kf = *(const bf16x8*)
        &Ksh[(cb * 16 + qrow) * 64 + (((ch * 4 + grp) ^ s7) << 3)];
      sc[cb] = MFMA16(kf, qf[ch], sc[cb]);   // S^T[k][q]
    }
  __builtin_amdgcn_s_setprio(0);

  if (diag) {
#pragma unroll
    for (int cb = 0; cb < 4; ++cb)
#pragma unroll
      for (int r = 0; r < 4; ++r)
        if (kk0 + cb * 16 + grp * 4 + r > qi) sc[cb][r] = -1e30f;
  }

  float a0 = fmaxf(fmaxf(sc[0][0], sc[0][1]), fmaxf(sc[0][2], sc[0][3]));
  float a1 = fmaxf(fmaxf(sc[1][0], sc[1][1]), fmaxf(sc[1][2], sc[1][3]));
  float a2 = fmaxf(fmaxf(sc[2][0], sc[2][1]), fmaxf(sc[2][2], sc[2][3]));
  float a3 = fmaxf(fmaxf(sc[3][0], sc[3][1]), fmaxf(sc[3][2], sc[3][3]));
  float pm = fmaxf(fmaxf(a0, a1), fmaxf(a2, a3));

  if (__any(pm > m + 8.f)) {     // defer-max: rescale only when needed
    float px = fmaxf(pm, __shfl_xor(pm, 16));
    px = fmaxf(px, __shfl_xor(px, 32));
    const float mn = fmaxf(m, px);
    const float scl = exp2f(m - mn);
    m = mn;
    l *= scl;
#pragma unroll
    for (int hb = 0; hb < 4; ++hb)
#pragma unroll
      for (int r = 0; r < 4; ++r) o[hb][r] *= scl;
  }

#pragma unroll
  for (int cb = 0; cb < 4; ++cb) {
    bf16x4 pk;
#pragma unroll
    for (int r = 0; r < 4; ++r) {
      float p = exp2f(sc[cb][r] - m);
      l += p;
      pk[r] = (bf16)p;
    }
    *(bf16x4*)&Pw[qrow * 64 + (((((cb << 1) | (grp >> 1)) ^ s7) << 3)) +
                  ((grp & 1) << 2)] = pk;
  }

  __builtin_amdgcn_s_setprio(1);
#pragma unroll
  for (int ch = 0; ch < 2; ++ch) {
    bf16x8 pa = *(const bf16x8*)
      &Pw[qrow * 64 + (((ch * 4 + grp) ^ s7) << 3)];
#pragma unroll
    for (int hb = 0; hb < 4; ++hb) {
      bf16x8 vf = *(const bf16x8*)
        &Vsh[(hb * 16 + qrow) * 64 + (((ch * 4 + grp) ^ s7) << 3)];
      o[hb] = MFMA16(vf, pa, o[hb]);         // O^T[hd][q]
    }
  }
  __builtin_amdgcn_s_setprio(0);
}

// ---------------- flash attention, causal, 8 waves, k-parity split -------
// r11 structure + (a) double-buffered group-private K/V -> ONE barrier per
// round (writes of tile r+1 target the buffer whose readers finished at the
// PREVIOUS barrier); (b) XOR-swizzled unpadded LDS (80 KB total -> still 2
// blocks/CU); (c) defer-max softmax. grid (32, 16): x = bh, y = j.
__global__ __launch_bounds__(512, 4)
void attn_k(const bf16* __restrict__ q, const bf16* __restrict__ k,
            const bf16* __restrict__ vt, bf16* __restrict__ out) {
  __shared__ __align__(16) char smem[81920];
  // KV region: [group][buf][K=0/V=1][64*64] bf16 = 64 KB
  bf16* KV = (bf16*)smem;
  // P region: [8 waves][16][64] bf16 = 16 KB
  bf16* Pr = (bf16*)(smem + 65536);
  // merge overlays (used after the k-loop, inside KV region)
  auto MO = (float(*)[2][16][68])smem;             // [4][2][16][68] f32
  auto ML = (float(*)[2][16][2])(smem + 36864);    // [4][2][16][2] f32

  const int tid = threadIdx.x;
  const int w = tid >> 6, lane = tid & 63;
  const int h = w >> 2, wl = w & 3;                // group, pair-index
  const int qrow = lane & 15, grp = lane >> 4;
  const int bh = blockIdx.x, j = blockIdx.y;
  const int b = bh >> 4, hh = bh & (NH - 1);
  const int tA = j, tB = 31 - j;

  const bf16* qb = q + (size_t)bh * NS * NHD;
  const bf16* kb = k + (size_t)bh * NS * NHD;
  const bf16* vb = vt + (size_t)bh * NHD * NS;

  const int nA = (j >= h) ? (((j - h) >> 1) + 1) : 0;   // group's tile-A rounds
  const int nB = (((31 - j) - h) >> 1) + 1;             // group's tile-B rounds
  const int len = nA + nB;                              // 17 (h=0) or 16 (h=1)

  const int q0A = tA * 64 + wl * 16, q0B = tB * 64 + wl * 16;
  bf16x8 qfA[2], qfB[2];
#pragma unroll
  for (int ch = 0; ch < 2; ++ch) {
    qfA[ch] = *(const bf16x8*)&qb[(size_t)(q0A + qrow) * NHD + ch * 32 + grp * 8];
    qfB[ch] = *(const bf16x8*)&qb[(size_t)(q0B + qrow) * NHD + ch * 32 + grp * 8];
  }

  f32x4 oA[4] = {}, oB[4] = {};
  float mA = -1e30f, lA = 0.f, mB = -1e30f, lB = 0.f;

  // group-private staging slots: 256 threads cover 64x64 K + 64x64 V
  const int local = tid & 255;
  const int r0 = local >> 3;                     // rows r0, r0+32
  const int c0 = (local & 7) * 8;                // linear global col
  const int sw = (((local & 7) ^ (r0 & 7)) << 3);  // swizzled LDS col

  bf16* Pw = Pr + w * 1024;
  auto Kb = [&](int buf) { return KV + ((h * 2 + buf) * 2 + 0) * 4096; };
  auto Vb = [&](int buf) { return KV + ((h * 2 + buf) * 2 + 1) * 4096; };

  bf16x8 ka0, ka1, va0, va1;
  auto load_round = [&](int r) {
    const bool isA = r < nA;
    const int kt = isA ? (h + 2 * r) : (h + 2 * (r - nA));
    const int kk0 = kt * 64;
    ka0 = *(const bf16x8*)&kb[(size_t)(kk0 + r0) * NHD + c0];
    ka1 = *(const bf16x8*)&kb[(size_t)(kk0 + r0 + 32) * NHD + c0];
    va0 = *(const bf16x8*)&vb[(size_t)r0 * NS + kk0 + c0];
    va1 = *(const bf16x8*)&vb[(size_t)(r0 + 32) * NS + kk0 + c0];
  };
  auto store_tile = [&](int buf) {
    bf16* Ksc = Kb(buf);
    bf16* Vsc = Vb(buf);
    *(bf16x8*)&Ksc[r0 * 64 + sw]        = ka0;
    *(bf16x8*)&Ksc[(r0 + 32) * 64 + sw] = ka1;   // (r0+32)&7 == r0&7
    *(bf16x8*)&Vsc[r0 * 64 + sw]        = va0;
    *(bf16x8*)&Vsc[(r0 + 32) * 64 + sw] = va1;
  };

  // prologue: tile 0 -> buf 0; issue tile-1 loads
  load_round(0);
  store_tile(0);
  load_round(1);           // len >= 16 always
  block_sync_lds();        // publish buf0 (global loads stay in flight)

  for (int r = 0; r < 17; ++r) {
    const int cur = r & 1;
    const bool act = r < len;
    if (r + 1 < len) store_tile(cur ^ 1);   // tile r+1; its readers synced at r-1
    if (r + 2 < len) load_round(r + 2);     // issue next loads under compute
    if (act) {
      const bool isA = r < nA;
      const int kt = isA ? (h + 2 * r) : (h + 2 * (r - nA));
      if (isA)
        attn_tile(Kb(cur), Vb(cur), Pw, qfA, oA, mA, lA,
                  q0A + qrow, kt * 64, kt == tA, qrow, grp);
      else
        attn_tile(Kb(cur), Vb(cur), Pw, qfB, oB, mB, lB,
                  q0B + qrow, kt * 64, kt == tB, qrow, grp);
    }
    block_sync_lds();      // single barrier: publishes writes, guards WAR
  }

  // reduce l across the 4 lane-groups sharing each q-row
  lA += __shfl_xor(lA, 16); lA += __shfl_xor(lA, 32);
  lB += __shfl_xor(lB, 16); lB += __shfl_xor(lB, 32);

  __syncthreads();   // all LDS traffic done before overlay reuse

  if (h == 1) {      // publish group-1 partials (fp32)
#pragma unroll
    for (int hb = 0; hb < 4; ++hb) {
      *(f32x4*)&MO[wl][0][qrow][hb * 16 + grp * 4] = oA[hb];
      *(f32x4*)&MO[wl][1][qrow][hb * 16 + grp * 4] = oB[hb];
    }
    if (grp == 0) {
      ML[wl][0][qrow][0] = mA; ML[wl][0][qrow][1] = lA;
      ML[wl][1][qrow][0] = mB; ML[wl][1][qrow][1] = lB;
    }
  }
  __syncthreads();

  if (h == 0) {      // merge + store
#pragma unroll
    for (int sub = 0; sub < 2; ++sub) {
      const float m0 = sub ? mB : mA, l0 = sub ? lB : lA;
      const f32x4* o0 = sub ? oB : oA;
      const float m1 = ML[wl][sub][qrow][0], l1 = ML[wl][sub][qrow][1];
      const float mm = fmaxf(m0, m1);
      const float s0 = exp2f(m0 - mm), s1 = exp2f(m1 - mm);
      const float inv = 1.f / (l0 * s0 + l1 * s1);
      const int s = (sub ? q0B : q0A) + qrow;
      bf16* op = out + (size_t)(b * NS + s) * ND + hh * NHD + grp * 4;
#pragma unroll
      for (int hb = 0; hb < 4; ++hb) {
        f32x4 o1 = *(const f32x4*)&MO[wl][sub][qrow][hb * 16 + grp * 4];
        bf16x4 ov = { (bf16)((o0[hb][0] * s0 + o1[0] * s1) * inv),
                      (bf16)((o0[hb][1] * s0 + o1[1] * s1) * inv),
                      (bf16)((o0[hb][2] * s0 + o1[2] * s1) * inv),
                      (bf16)((o0[hb][3] * s0 + o1[3] * s1) * inv) };
        *(bf16x4*)&op[hb * 16] = ov;
      }
    }
  }
}

// -------------------------------------------------------------------------
extern "C" void kernel_launch(void* const* d_in, const int* in_sizes, int n_in,
                              void* d_out, int out_size, void* d_ws, size_t ws_size,
                              hipStream_t stream) {
  const float* Q  = (const float*)d_in[0];
  const float* K  = (const float*)d_in[1];
  const float* V  = (const float*)d_in[2];
  // d_in[3] = mask (causal, known analytically -> unused)
  const float* fc = (const float*)d_in[4];
  const float* fs = (const float*)d_in[5];
  const float* wq = (const float*)d_in[6];
  const float* bq = (const float*)d_in[7];
  const float* wk = (const float*)d_in[8];
  const float* bk = (const float*)d_in[9];
  const float* wv = (const float*)d_in[10];
  const float* bv = (const float*)d_in[11];
  const float* wo = (const float*)d_in[12];
  const float* bo = (const float*)d_in[13];
  float* out = (float*)d_out;
  bf16* ws = (bf16*)d_ws;

  const size_t MB_ = 1024 * 1024;  // elements
  bf16* Qbf  = ws;                     // 3 x 4M elems (Q,K,V bf16)
  bf16* Wqkv = ws + 12 * MB_;          // 3 x 1M (wq, wk, wv)
  bf16* Wo   = ws + 15 * MB_;          // 1M
  bf16* qp   = ws + 16 * MB_;          // q' [BH,S,HD] 4M
  bf16* kp   = ws + 20 * MB_;          // k' 4M
  bf16* vtp  = ws + 28 * MB_;          // v transposed [BH,HD,S] 4M (direct)
  bf16* aout = ws + 32 * MB_;          // attention output [M, D] 4M

  cvt3<<<dim3(4096, 3), 256, 0, stream>>>(Q, K, V, Qbf, 1048576);
  cvt_w4<<<dim3(1024, 4), 256, 0, stream>>>(wq, wk, wv, wo, Wqkv, 262144);

  gemm_nt<0><<<768, 256, 0, stream>>>(Qbf, Wqkv, bq, bk, bv, fc, fs,
                                      qp, vtp, nullptr);

  attn_k<<<dim3(32, 16), 512, 0, stream>>>(qp, kp, vtp, aout);

  gemm_nt<1><<<512, 256, 0, stream>>>(aout, Wo, bo, bo, bo, fc, fs,
                                      nullptr, nullptr, out);
}